// Round 10
// baseline (299.489 us; speedup 1.0000x reference)
//
#include <hip/hip_runtime.h>

// Elman RNN via MFMA, register-chained recurrence, j-split across 4 waves.
//   H^T_{t+1} = tanh(W_hh * H^T_t + W_ih * x_t^T + b),  out = sigmoid(fc_w.h_T + fc_b)
//
// mfma_f32_16x16x16f16 layouts (HW-verified, absmax 3.9e-3):
//   A[m][k]: m = lane&15, k = quad*4 + i
//   B[k][n]: k = quad*4 + i, n = lane&15
//   D[m][n]: n = lane&15, m = quad*4 + reg
// => a wave's packed D tile (m-tile w) IS the B-frag of k-tile kt=w for the
//    next step, in the same lane. Waves exchange B-frags through LDS with a
//    raw `s_waitcnt lgkmcnt(0); s_barrier` (vmcnt stays in flight).
//
// Scoreboard (per-dispatch): R3 = 166; R7 (pre-scaled weights + 3-level
// tanh) = 149.7; R8 (parallel foreign MFMA roots) = 144.2 BEST. Failures:
// 1-wave register-closed 361; frcp_rn 174; pre-barrier gap work 270; K=32
// mfma 284. R8 gained only ~28cy (not 100) => MFMA dep latency ~40-50cy.
// Step = 674cy: reads ~130-145 + MFMA ~50 + adds 16 + tanh ~45 + pack +
// write/ack ~50 + barrier ~75 + ~170cy in-order issue. No 100cy+ segment
// left; all structural departures measured worse.
//
// R9 (final shavings, R8 skeleton unchanged):
//  (a) local accumulators folded into foreign MFMAs' C: f1's C = ca
//      (bias+ih0->own chain, ready ~110cy < read1 ~130cy), f2's C = cb
//      (ih1). Add tree 4 adds/2 levels -> 2 adds, ONE dependent add after
//      the last MFMA.
//  (b) final 4 steps peeled: main loop has no tn clamp; peeled block does
//      no refill at all.

#define RN 2048
#define RT 512
#define RI 32
#define RH 64

typedef _Float16 h4 __attribute__((ext_vector_type(4)));
typedef float    f4 __attribute__((ext_vector_type(4)));

__device__ __forceinline__ int pk2(float a, float b) {
    return __builtin_bit_cast(int, __builtin_amdgcn_cvt_pkrtz(a, b));
}
__device__ __forceinline__ h4 pack4(float a, float b, float c, float d) {
    union { h4 v; int i[2]; } u;
    u.i[0] = pk2(a, b);
    u.i[1] = pk2(c, d);
    return u.v;
}
__device__ __forceinline__ h4 packf4(f4 v) { return pack4(v[0], v[1], v[2], v[3]); }

// acc is pre-scaled: acc = 2*log2(e) * z.  tanh(z) = 1 - 2/(2^acc + 1).
__device__ __forceinline__ float tanh_pre(float acc) {
    float e = __builtin_amdgcn_exp2f(acc);        // v_exp_f32
    float r = __builtin_amdgcn_rcpf(e + 1.0f);    // v_rcp_f32
    return fmaf(-2.0f, r, 1.0f);                  // v_fma_f32
}

#define TSCALE 2.8853900817779268f   // 2*log2(e)

__global__ __launch_bounds__(256, 1) void rnn_mfma4(
    const float* __restrict__ x,
    const float* __restrict__ W_ih,
    const float* __restrict__ W_hh,
    const float* __restrict__ b_ih,
    const float* __restrict__ b_hh,
    const float* __restrict__ fc_w,
    const float* __restrict__ fc_b,
    float* __restrict__ out)
{
    const int tid  = threadIdx.x;
    const int w    = tid >> 6;      // wave id = m-tile
    const int lane = tid & 63;
    const int col  = lane & 15;     // sample within group
    const int quad = lane >> 4;     // 0..3
    const int g    = blockIdx.x;

    // h exchange: [buf][kt*64 + lane] -> 8B B-frag. 2-way bank alias only.
    __shared__ unsigned long long hb[2][4 * 64];
    __shared__ float ob[4][16];

    // ---- A-frags for my m-tile, kt ROTATED: slot i holds kt=(w+i)&3 ----
    // slot 0 = own tile (register-local B), slots 1..3 = foreign (LDS B).
    // All weight frags and the bias are PRE-SCALED by 2*log2(e).
    h4 Ahh[4];
#pragma unroll
    for (int i = 0; i < 4; ++i) {
        const int kt = (w + i) & 3;
        f4 v = *(const f4*)(W_hh + (w * 16 + col) * RH + kt * 16 + quad * 4);
        Ahh[i] = packf4(v * TSCALE);
    }
    h4 Aih[2];
#pragma unroll
    for (int kt = 0; kt < 2; ++kt) {
        f4 v = *(const f4*)(W_ih + (w * 16 + col) * RI + kt * 16 + quad * 4);
        Aih[kt] = packf4(v * TSCALE);
    }
    f4 biasv;
    {
        f4 bi = *(const f4*)(b_ih + w * 16 + quad * 4);
        f4 bh = *(const f4*)(b_hh + w * 16 + quad * 4);
        biasv = (bi + bh) * TSCALE;
    }

    // ---- x stream for this lane's sample, 4-step static ring ----
    const float* xb = x + (size_t)(g * 16 + col) * (RT * RI);
    f4 xbuf[4][2];
#pragma unroll
    for (int s = 0; s < 4; ++s) {
        xbuf[s][0] = *(const f4*)(xb + s * RI + quad * 4);
        xbuf[s][1] = *(const f4*)(xb + s * RI + 16 + quad * 4);
    }

    // h0 = ones, already in B-frag layout. Bh[i] corresponds to kt=(w+i)&3;
    // Bh[0] is my OWN tile (from my local pack, never from LDS).
    h4 Bh[4];
#pragma unroll
    for (int i = 0; i < 4; ++i) Bh[i] = pack4(1.f, 1.f, 1.f, 1.f);
    f4 hv; // f32 h of final step (my m-tile rows), for epilogue

    // One recurrence step. REFILL: main loop refills the x ring (no clamp
    // needed); peeled tail skips refill entirely.
#define RNN_STEP(T4, S, REFILL)                                                        \
    {                                                                                  \
        const int t = (T4) + (S);                                                      \
        h4 bx0 = packf4(xbuf[S][0]);                                                   \
        h4 bx1 = packf4(xbuf[S][1]);                                                   \
        if (REFILL) {                                                                  \
            const int tn = t + 4;                                                      \
            xbuf[S][0] = *(const f4*)(xb + tn * RI + quad * 4);                        \
            xbuf[S][1] = *(const f4*)(xb + tn * RI + 16 + quad * 4);                   \
        }                                                                              \
        const f4 z{0.f, 0.f, 0.f, 0.f};                                                \
        f4 ca = __builtin_amdgcn_mfma_f32_16x16x16f16(Aih[0], bx0, biasv, 0, 0, 0);    \
        f4 cb = __builtin_amdgcn_mfma_f32_16x16x16f16(Aih[1], bx1, z, 0, 0, 0);        \
        ca = __builtin_amdgcn_mfma_f32_16x16x16f16(Ahh[0], Bh[0], ca, 0, 0, 0);        \
        f4 f1 = __builtin_amdgcn_mfma_f32_16x16x16f16(Ahh[1], Bh[1], ca, 0, 0, 0);     \
        f4 f2 = __builtin_amdgcn_mfma_f32_16x16x16f16(Ahh[2], Bh[2], cb, 0, 0, 0);     \
        f4 f3 = __builtin_amdgcn_mfma_f32_16x16x16f16(Ahh[3], Bh[3], z, 0, 0, 0);      \
        f4 acc = (f1 + f2) + f3;   /* acc = 2*log2(e) * z */                           \
        hv[0] = tanh_pre(acc[0]);                                                      \
        hv[1] = tanh_pre(acc[1]);                                                      \
        hv[2] = tanh_pre(acc[2]);                                                      \
        hv[3] = tanh_pre(acc[3]);                                                      \
        const int p = t & 1;                                                           \
        h4 hpk = packf4(hv);                                                           \
        hb[p][w * 64 + lane] = __builtin_bit_cast(unsigned long long, hpk);            \
        asm volatile("s_waitcnt lgkmcnt(0)\n\ts_barrier" ::: "memory");                \
        Bh[0] = hpk;                                                                   \
        Bh[1] = __builtin_bit_cast(h4, hb[p][(((w + 1) & 3)) * 64 + lane]);            \
        Bh[2] = __builtin_bit_cast(h4, hb[p][(((w + 2) & 3)) * 64 + lane]);            \
        Bh[3] = __builtin_bit_cast(h4, hb[p][(((w + 3) & 3)) * 64 + lane]);            \
    }

    // main loop: steps 0 .. RT-5, clamp-free refill (tn <= RT-1)
    for (int t4 = 0; t4 < RT - 4; t4 += 4) {
        RNN_STEP(t4, 0, 1)
        RNN_STEP(t4, 1, 1)
        RNN_STEP(t4, 2, 1)
        RNN_STEP(t4, 3, 1)
    }
    // peeled tail: steps RT-4 .. RT-1, no refill
    RNN_STEP(RT - 4, 0, 0)
    RNN_STEP(RT - 4, 1, 0)
    RNN_STEP(RT - 4, 2, 0)
    RNN_STEP(RT - 4, 3, 0)
#undef RNN_STEP

    // ---- epilogue: out[n] = sigmoid(sum_j fc_w[j] h[n][j] + fc_b) ----
    {
        f4 wv = *(const f4*)(fc_w + w * 16 + quad * 4);
        float s = wv[0] * hv[0] + wv[1] * hv[1] + wv[2] * hv[2] + wv[3] * hv[3];
        s += __shfl_xor(s, 16, 64);
        s += __shfl_xor(s, 32, 64); // all lanes: partial over my 16 hidden units
        if (quad == 0) ob[w][col] = s;
        __syncthreads();
        if (w == 0 && lane < 16) {
            float logit = ob[0][lane] + ob[1][lane] + ob[2][lane] + ob[3][lane] + fc_b[0];
            out[g * 16 + lane] = __fdividef(1.0f, 1.0f + __expf(-logit));
        }
    }
}

extern "C" void kernel_launch(void* const* d_in, const int* in_sizes, int n_in,
                              void* d_out, int out_size, void* d_ws, size_t ws_size,
                              hipStream_t stream) {
    rnn_mfma4<<<RN / 16, 256, 0, stream>>>(
        (const float*)d_in[0], (const float*)d_in[1], (const float*)d_in[2],
        (const float*)d_in[3], (const float*)d_in[4], (const float*)d_in[5],
        (const float*)d_in[6], (float*)d_out);
}

// Round 11
// 285.107 us; speedup vs baseline: 1.0504x; 1.0504x over previous
//
#include <hip/hip_runtime.h>

// Elman RNN via MFMA, register-chained recurrence, j-split across 4 waves.
//   H^T_{t+1} = tanh(W_hh * H^T_t + W_ih * x_t^T + b),  out = sigmoid(fc_w.h_T + fc_b)
//
// mfma_f32_16x16x16f16 layouts (HW-verified, absmax 3.9e-3):
//   A[m][k]: m = lane&15, k = quad*4 + i
//   B[k][n]: k = quad*4 + i, n = lane&15
//   D[m][n]: n = lane&15, m = quad*4 + reg
// => a wave's packed D tile (m-tile w) IS the B-frag of k-tile kt=w for the
//    next step, in the same lane. Waves exchange B-frags through LDS with a
//    raw `s_waitcnt lgkmcnt(0); s_barrier` (vmcnt stays in flight).
//
// FINAL (R8 skeleton, measured best 144.2us/dispatch, bench 283us):
// scoreboard of everything tried (per-dispatch):
//   R3 2x3-chain skeleton ................ 166
//   R7 = R3 + pre-scaled weights + tanh3 . 149.7
//   R8 = R7 + parallel foreign roots ..... 144.2  << THIS FILE
//   1-wave register-closed (no barrier) .. 361  (no latency hiding)
//   3x2 chains + frcp_rn ................. 174  (frcp_rn multi-inst)
//   pre-barrier gap work ................. 270  (delays barrier arrival)
//   K=32 mfma ............................ 284  (dep latency + cat() movs)
//   C-fold f1.C=ca / f2.C=cb + tail peel . 158  (in-order issue: f1 stalls
//        at issue until ca completes, blocking f2/f3 behind it — R8's
//        parallel roots let the ca chain overlap the foreign MFMAs)
// Step ~674cy = reads ~130-145 + MFMA ~50 + add tree ~16 + tanh ~45 +
// pack + write/ack ~50 + barrier ~75 + in-order issue ~170. No segment
// >100cy remains; 512 serial steps x 4-wave rendezvous = the floor.

#define RN 2048
#define RT 512
#define RI 32
#define RH 64

typedef _Float16 h4 __attribute__((ext_vector_type(4)));
typedef float    f4 __attribute__((ext_vector_type(4)));

__device__ __forceinline__ int pk2(float a, float b) {
    return __builtin_bit_cast(int, __builtin_amdgcn_cvt_pkrtz(a, b));
}
__device__ __forceinline__ h4 pack4(float a, float b, float c, float d) {
    union { h4 v; int i[2]; } u;
    u.i[0] = pk2(a, b);
    u.i[1] = pk2(c, d);
    return u.v;
}
__device__ __forceinline__ h4 packf4(f4 v) { return pack4(v[0], v[1], v[2], v[3]); }

// acc is pre-scaled: acc = 2*log2(e) * z.  tanh(z) = 1 - 2/(2^acc + 1).
__device__ __forceinline__ float tanh_pre(float acc) {
    float e = __builtin_amdgcn_exp2f(acc);        // v_exp_f32
    float r = __builtin_amdgcn_rcpf(e + 1.0f);    // v_rcp_f32
    return fmaf(-2.0f, r, 1.0f);                  // v_fma_f32
}

#define TSCALE 2.8853900817779268f   // 2*log2(e)

__global__ __launch_bounds__(256, 1) void rnn_mfma4(
    const float* __restrict__ x,
    const float* __restrict__ W_ih,
    const float* __restrict__ W_hh,
    const float* __restrict__ b_ih,
    const float* __restrict__ b_hh,
    const float* __restrict__ fc_w,
    const float* __restrict__ fc_b,
    float* __restrict__ out)
{
    const int tid  = threadIdx.x;
    const int w    = tid >> 6;      // wave id = m-tile
    const int lane = tid & 63;
    const int col  = lane & 15;     // sample within group
    const int quad = lane >> 4;     // 0..3
    const int g    = blockIdx.x;

    // h exchange: [buf][kt*64 + lane] -> 8B B-frag. 2-way bank alias only.
    __shared__ unsigned long long hb[2][4 * 64];
    __shared__ float ob[4][16];

    // ---- A-frags for my m-tile, kt ROTATED: slot i holds kt=(w+i)&3 ----
    // slot 0 = own tile (register-local B), slots 1..3 = foreign (LDS B).
    // All weight frags and the bias are PRE-SCALED by 2*log2(e).
    h4 Ahh[4];
#pragma unroll
    for (int i = 0; i < 4; ++i) {
        const int kt = (w + i) & 3;
        f4 v = *(const f4*)(W_hh + (w * 16 + col) * RH + kt * 16 + quad * 4);
        Ahh[i] = packf4(v * TSCALE);
    }
    h4 Aih[2];
#pragma unroll
    for (int kt = 0; kt < 2; ++kt) {
        f4 v = *(const f4*)(W_ih + (w * 16 + col) * RI + kt * 16 + quad * 4);
        Aih[kt] = packf4(v * TSCALE);
    }
    f4 biasv;
    {
        f4 bi = *(const f4*)(b_ih + w * 16 + quad * 4);
        f4 bh = *(const f4*)(b_hh + w * 16 + quad * 4);
        biasv = (bi + bh) * TSCALE;
    }

    // ---- x stream for this lane's sample, 4-step static ring ----
    const float* xb = x + (size_t)(g * 16 + col) * (RT * RI);
    f4 xbuf[4][2];
#pragma unroll
    for (int s = 0; s < 4; ++s) {
        xbuf[s][0] = *(const f4*)(xb + s * RI + quad * 4);
        xbuf[s][1] = *(const f4*)(xb + s * RI + 16 + quad * 4);
    }

    // h0 = ones, already in B-frag layout. Bh[i] corresponds to kt=(w+i)&3;
    // Bh[0] is my OWN tile (from my local pack, never from LDS).
    h4 Bh[4];
#pragma unroll
    for (int i = 0; i < 4; ++i) Bh[i] = pack4(1.f, 1.f, 1.f, 1.f);
    f4 hv; // f32 h of final step (my m-tile rows), for epilogue

    for (int t4 = 0; t4 < RT; t4 += 4) {
#pragma unroll
        for (int s = 0; s < 4; ++s) {
            const int t = t4 + s;
            h4 bx0 = packf4(xbuf[s][0]);
            h4 bx1 = packf4(xbuf[s][1]);
            int tn = t + 4; if (tn > RT - 1) tn = RT - 1;
            xbuf[s][0] = *(const f4*)(xb + tn * RI + quad * 4);
            xbuf[s][1] = *(const f4*)(xb + tn * RI + 16 + quad * 4);

            // Depth-1 foreign dataflow: local roots first (operands ready at
            // entry, issue into the ds_read latency window), then the three
            // INDEPENDENT foreign MFMAs at read-complete, then the local
            // depth-2 own MFMA (its C arrives ~read-time). f4 add tree merges.
            const f4 z{0.f, 0.f, 0.f, 0.f};
            f4 ca = __builtin_amdgcn_mfma_f32_16x16x16f16(Aih[0], bx0, biasv, 0, 0, 0);
            f4 cb = __builtin_amdgcn_mfma_f32_16x16x16f16(Aih[1], bx1, z, 0, 0, 0);
            f4 f1 = __builtin_amdgcn_mfma_f32_16x16x16f16(Ahh[1], Bh[1], z, 0, 0, 0); // foreign 1
            f4 f2 = __builtin_amdgcn_mfma_f32_16x16x16f16(Ahh[2], Bh[2], z, 0, 0, 0); // foreign 2
            f4 f3 = __builtin_amdgcn_mfma_f32_16x16x16f16(Ahh[3], Bh[3], z, 0, 0, 0); // foreign 3
            ca = __builtin_amdgcn_mfma_f32_16x16x16f16(Ahh[0], Bh[0], ca, 0, 0, 0);   // own, local
            f4 acc = (ca + cb) + ((f1 + f2) + f3);   // acc = 2*log2(e) * z

            hv[0] = tanh_pre(acc[0]);
            hv[1] = tanh_pre(acc[1]);
            hv[2] = tanh_pre(acc[2]);
            hv[3] = tanh_pre(acc[3]);

            // publish my D tile as next step's B-frag kt = w
            const int p = t & 1;
            h4 hpk = packf4(hv);
            hb[p][w * 64 + lane] = __builtin_bit_cast(unsigned long long, hpk);
            // RAW BARRIER: wait only on the LDS write (lgkmcnt), NOT on the
            // global x-prefetch (vmcnt) — loads stay in flight across steps.
            asm volatile("s_waitcnt lgkmcnt(0)\n\ts_barrier" ::: "memory");
            Bh[0] = hpk; // own tile, no LDS round-trip
            Bh[1] = __builtin_bit_cast(h4, hb[p][(((w + 1) & 3)) * 64 + lane]);
            Bh[2] = __builtin_bit_cast(h4, hb[p][(((w + 2) & 3)) * 64 + lane]);
            Bh[3] = __builtin_bit_cast(h4, hb[p][(((w + 3) & 3)) * 64 + lane]);
        }
    }

    // ---- epilogue: out[n] = sigmoid(sum_j fc_w[j] h[n][j] + fc_b) ----
    {
        f4 wv = *(const f4*)(fc_w + w * 16 + quad * 4);
        float s = wv[0] * hv[0] + wv[1] * hv[1] + wv[2] * hv[2] + wv[3] * hv[3];
        s += __shfl_xor(s, 16, 64);
        s += __shfl_xor(s, 32, 64); // all lanes: partial over my 16 hidden units
        if (quad == 0) ob[w][col] = s;
        __syncthreads();
        if (w == 0 && lane < 16) {
            float logit = ob[0][lane] + ob[1][lane] + ob[2][lane] + ob[3][lane] + fc_b[0];
            out[g * 16 + lane] = __fdividef(1.0f, 1.0f + __expf(-logit));
        }
    }
}

extern "C" void kernel_launch(void* const* d_in, const int* in_sizes, int n_in,
                              void* d_out, int out_size, void* d_ws, size_t ws_size,
                              hipStream_t stream) {
    rnn_mfma4<<<RN / 16, 256, 0, stream>>>(
        (const float*)d_in[0], (const float*)d_in[1], (const float*)d_in[2],
        (const float*)d_in[3], (const float*)d_in[4], (const float*)d_in[5],
        (const float*)d_in[6], (float*)d_out);
}